// Round 3
// baseline (200.285 us; speedup 1.0000x reference)
//
#include <hip/hip_runtime.h>

typedef unsigned short ushort_t;
typedef __attribute__((ext_vector_type(8))) short short8;
typedef __attribute__((ext_vector_type(4))) float f32x4;

#define DIMC 512
#define PN   32768                  // 8*64*64 spatial positions
#define SQRTC 22.627416997969522f   // sqrt(512)

__device__ __forceinline__ ushort_t f2bf(float f) {
  unsigned int u = __float_as_uint(f);
  unsigned int r = u + 0x7fffu + ((u >> 16) & 1u);   // round-to-nearest-even
  return (ushort_t)(r >> 16);
}
__device__ __forceinline__ unsigned int pack2(float lo, float hi) {
  return ((unsigned int)f2bf(hi) << 16) | (unsigned int)f2bf(lo);
}

// ---------------- fused bias: fb[o] = sum_k w_proj[o,k]*b_qkv[1024+k] + b_proj[o]
__global__ __launch_bounds__(256) void k_fb(const float* __restrict__ wp,
                                            const float* __restrict__ bqkv,
                                            const float* __restrict__ bproj,
                                            float* __restrict__ fb) {
  int wave = threadIdx.x >> 6;
  int lane = threadIdx.x & 63;
  int o = blockIdx.x * 4 + wave;          // grid 128 -> o in [0,512)
  float part = 0.f;
#pragma unroll
  for (int i = 0; i < 8; ++i) {
    int k = lane + i * 64;
    part += wp[o * DIMC + k] * bqkv[1024 + k];
  }
  for (int off = 32; off; off >>= 1) part += __shfl_down(part, off, 64);
  if (lane == 0) fb[o] = part + bproj[o];
}

// ---------------- per-position inverse norm scale: s[p] = sqrt(512)/max(||x[:,p]||,1e-12)
__global__ __launch_bounds__(256) void k_norm(const float* __restrict__ x,
                                              float* __restrict__ s) {
  __shared__ float red[8 * 128];
  int tid = threadIdx.x;
  int pg = tid & 31;        // 32 p-groups of 4 positions
  int cl = tid >> 5;        // 8 channel lanes
  int pbase = blockIdx.x * 128 + pg * 4;   // grid 256 -> 32768 positions
  float ss[4] = {0.f, 0.f, 0.f, 0.f};
  for (int c = cl; c < DIMC; c += 8) {
    float4 v = *(const float4*)(x + (long)c * PN + pbase);   // coalesced f32x4
    ss[0] += v.x * v.x;
    ss[1] += v.y * v.y;
    ss[2] += v.z * v.z;
    ss[3] += v.w * v.w;
  }
#pragma unroll
  for (int i = 0; i < 4; ++i) red[cl * 128 + pg * 4 + i] = ss[i];
  __syncthreads();
  if (tid < 128) {
    float t = 0.f;
#pragma unroll
    for (int c = 0; c < 8; ++c) t += red[c * 128 + tid];
    float nrm = fmaxf(sqrtf(t), 1e-12f);
    s[blockIdx.x * 128 + tid] = SQRTC / nrm;
  }
}

// ---------------- MFMA GEMM: C[M][N] = A[M][512] @ B[512][N], both row-major.
// A dtype templated (f32 source converted at staging, or bf16 precomputed).
// B is f32 source, converted to bf16 at staging.
// EPI 0: C = (A@B) * gamma[col]                     (weight fusion, bf16 out)
// EPI 1: C = xid[row,col] + fb[row] + s[col]*(A@B)  (main, f32 out)
template <int EPI, typename AT>
__global__ __launch_bounds__(256) void k_gemm(
    const AT* __restrict__ A,
    const float* __restrict__ B,
    int N,
    void* __restrict__ Cv,
    const float* __restrict__ gamma,
    const float* __restrict__ xid,
    const float* __restrict__ fb,
    const float* __restrict__ s) {
  __shared__ ushort_t As[128 * 64];   // [o][k], rows of 64 (bf16)
  __shared__ ushort_t Bs[64 * 128];   // [k][p], rows of 128 (bf16)
  int tid = threadIdx.x;
  int p0 = blockIdx.x * 128;
  int o0 = blockIdx.y * 128;
  int wave = tid >> 6, lane = tid & 63;
  int wo = (wave & 1) * 64, wp = (wave >> 1) * 64;
  int q = lane >> 4, ln = lane & 15;

  f32x4 zero = {0.f, 0.f, 0.f, 0.f};
  f32x4 acc[4][4];
#pragma unroll
  for (int i = 0; i < 4; ++i)
#pragma unroll
    for (int j = 0; j < 4; ++j) acc[i][j] = zero;

  int ar = tid >> 3;            // A stage: 32 rows per iter
  int ac = (tid & 7) * 8;
  int br = tid >> 4;            // B stage: 16 rows per iter
  int bc = (tid & 15) * 8;

  for (int kc = 0; kc < DIMC; kc += 64) {
    __syncthreads();
#pragma unroll
    for (int it = 0; it < 4; ++it) {
      int r = ar + it * 32;
      uint4 wa;
      if constexpr (sizeof(AT) == 4) {     // f32 source -> convert
        const float* ap = (const float*)A + (long)(o0 + r) * DIMC + kc + ac;
        float4 a0 = *(const float4*)ap;
        float4 a1 = *(const float4*)(ap + 4);
        wa.x = pack2(a0.x, a0.y); wa.y = pack2(a0.z, a0.w);
        wa.z = pack2(a1.x, a1.y); wa.w = pack2(a1.z, a1.w);
      } else {                             // bf16 source -> straight copy
        wa = *(const uint4*)((const ushort_t*)A + (long)(o0 + r) * DIMC + kc + ac);
      }
      *(uint4*)(&As[r * 64 + ac]) = wa;

      int kr = br + it * 16;
      const float* bp = B + (long)(kc + kr) * N + p0 + bc;
      float4 b0 = *(const float4*)bp;
      float4 b1 = *(const float4*)(bp + 4);
      uint4 wb;
      wb.x = pack2(b0.x, b0.y); wb.y = pack2(b0.z, b0.w);
      wb.z = pack2(b1.x, b1.y); wb.w = pack2(b1.z, b1.w);
      *(uint4*)(&Bs[kr * 128 + bc]) = wb;
    }
    __syncthreads();
#pragma unroll
    for (int ks = 0; ks < 2; ++ks) {
      int kb = ks * 32 + q * 8;
      short8 af[4], bfr[4];
#pragma unroll
      for (int mi = 0; mi < 4; ++mi) {
        int ol = wo + mi * 16 + ln;
        af[mi] = *(const short8*)(&As[ol * 64 + kb]);    // ds_read_b128
      }
#pragma unroll
      for (int ni = 0; ni < 4; ++ni) {
        int pl = wp + ni * 16 + ln;
        short8 t;
#pragma unroll
        for (int j = 0; j < 8; ++j) t[j] = (short)Bs[(kb + j) * 128 + pl];  // strided u16 (known-slow; fix after green)
        bfr[ni] = t;
      }
#pragma unroll
      for (int mi = 0; mi < 4; ++mi)
#pragma unroll
        for (int ni = 0; ni < 4; ++ni)
          acc[mi][ni] = __builtin_amdgcn_mfma_f32_16x16x32_bf16(af[mi], bfr[ni], acc[mi][ni], 0, 0, 0);
    }
  }

#pragma unroll
  for (int mi = 0; mi < 4; ++mi) {
    int obase = o0 + wo + mi * 16 + q * 4;
#pragma unroll
    for (int ni = 0; ni < 4; ++ni) {
      int p = p0 + wp + ni * 16 + ln;
      if (EPI == 0) {
        ushort_t* C = (ushort_t*)Cv;
        float g = gamma[p];
#pragma unroll
        for (int r = 0; r < 4; ++r)
          C[(long)(obase + r) * N + p] = f2bf(acc[mi][ni][r] * g);
      } else {
        float* C = (float*)Cv;              // f32 output (reference output dtype)
        float sv = s[p];
#pragma unroll
        for (int r = 0; r < 4; ++r) {
          int o = obase + r;
          C[(long)o * PN + p] = xid[(long)o * PN + p] + fb[o] + sv * acc[mi][ni][r];
        }
      }
    }
  }
}

extern "C" void kernel_launch(void* const* d_in, const int* in_sizes, int n_in,
                              void* d_out, int out_size, void* d_ws, size_t ws_size,
                              hipStream_t stream) {
  const float* x     = (const float*)d_in[0];
  const float* gamma = (const float*)d_in[1];
  const float* wqkv  = (const float*)d_in[2];
  const float* bqkv  = (const float*)d_in[3];
  const float* wproj = (const float*)d_in[4];
  const float* bproj = (const float*)d_in[5];

  char* ws = (char*)d_ws;
  ushort_t* Mp = (ushort_t*)ws;               // 512*512 bf16 fused weight (524288 B)
  float* fb = (float*)(ws + 524288);          // 512 f32 fused bias
  float* s  = (float*)(ws + 526336);          // 32768 f32 inverse-norm scales

  k_fb<<<dim3(128), dim3(256), 0, stream>>>(wproj, bqkv, bproj, fb);
  k_norm<<<dim3(256), dim3(256), 0, stream>>>(x, s);
  // Mp[o][c] = (sum_k wproj[o,k] * wqkv[1024+k, c]) * gamma[c]
  k_gemm<0, float><<<dim3(4, 4), dim3(256), 0, stream>>>(
      wproj, wqkv + 1024 * DIMC, DIMC, Mp, gamma, nullptr, nullptr, nullptr);
  // out[o][p] = x[o][p] + fb[o] + s[p] * sum_c Mp[o,c]*x[c,p]
  k_gemm<1, ushort_t><<<dim3(256, 4), dim3(256), 0, stream>>>(
      Mp, x, PN, d_out, nullptr, x, fb, s);
}

// Round 4
// 176.570 us; speedup vs baseline: 1.1343x; 1.1343x over previous
//
#include <hip/hip_runtime.h>

typedef unsigned short ushort_t;
typedef __attribute__((ext_vector_type(8))) short short8;
typedef __attribute__((ext_vector_type(4))) float f32x4;

#define DIMC 512
#define PN   32768                  // 8*64*64 spatial positions
#define SQRTC 22.627416997969522f   // sqrt(512)

__device__ __forceinline__ ushort_t f2bf(float f) {
  unsigned int u = __float_as_uint(f);
  unsigned int r = u + 0x7fffu + ((u >> 16) & 1u);   // round-to-nearest-even
  return (ushort_t)(r >> 16);
}

// ---------------- cast wproj f32 -> bf16 [o][k] (k-contiguous)
__global__ __launch_bounds__(256) void k_cast(const float* __restrict__ a,
                                              ushort_t* __restrict__ b) {
  int i = (blockIdx.x * 256 + threadIdx.x) * 4;     // grid 256 -> 262144 el
  float4 v = *(const float4*)(a + i);
  ushort_t o[4] = {f2bf(v.x), f2bf(v.y), f2bf(v.z), f2bf(v.w)};
  *(uint2*)(b + i) = *(const uint2*)o;
}

// ---------------- WvT[c][k'] = bf16(wqkv[(1024+k')*512 + c])  (transpose V-weight)
__global__ __launch_bounds__(64) void k_wvt(const float* __restrict__ wqkv,
                                            ushort_t* __restrict__ WvT) {
  int c = blockIdx.x;          // 512
  int k8 = threadIdx.x * 8;    // 64 threads * 8 = 512
  ushort_t tmp[8];
#pragma unroll
  for (int j = 0; j < 8; ++j)
    tmp[j] = f2bf(wqkv[(long)(1024 + k8 + j) * DIMC + c]);  // scattered reads, 1MB footprint (L2)
  *(uint4*)(WvT + (long)c * DIMC + k8) = *(const uint4*)tmp;
}

// ---------------- fused bias: fb[o] = sum_k w_proj[o,k]*b_qkv[1024+k] + b_proj[o]
__global__ __launch_bounds__(256) void k_fb(const float* __restrict__ wp,
                                            const float* __restrict__ bqkv,
                                            const float* __restrict__ bproj,
                                            float* __restrict__ fb) {
  int wave = threadIdx.x >> 6;
  int lane = threadIdx.x & 63;
  int o = blockIdx.x * 4 + wave;          // grid 128 -> o in [0,512)
  float part = 0.f;
#pragma unroll
  for (int i = 0; i < 8; ++i) {
    int k = lane + i * 64;
    part += wp[o * DIMC + k] * bqkv[1024 + k];
  }
  for (int off = 32; off; off >>= 1) part += __shfl_down(part, off, 64);
  if (lane == 0) fb[o] = part + bproj[o];
}

// ---------------- fused transpose+cast+norm:
//   xT[p][c] = bf16(x[c][p]);  s[p] = sqrt(512)/max(||x[:,p]||, 1e-12)
// Block: 64 p-positions x all 512 c, in two c-halves of 256 (LDS 64x264 bf16).
__global__ __launch_bounds__(256) void k_prep_x(const float* __restrict__ x,
                                                ushort_t* __restrict__ xT,
                                                float* __restrict__ s) {
  __shared__ ushort_t xt[64 * 264];      // 33.8 KB, row pad 264 (528B, 16B-aligned)
  __shared__ float red[16 * 64];
  int tid = threadIdx.x;
  long p0 = (long)blockIdx.x * 64;       // grid 512
  int cg = tid >> 4;                     // 16 c-lanes
  int p4 = (tid & 15) * 4;               // 16 p-groups of 4
  float ss0 = 0.f, ss1 = 0.f, ss2 = 0.f, ss3 = 0.f;
  for (int half = 0; half < 2; ++half) {
    __syncthreads();                     // protect xt vs previous writeout
#pragma unroll 4
    for (int pass = 0; pass < 16; ++pass) {
      int cl = pass * 16 + cg;           // local col 0..255
      int c = half * 256 + cl;
      float4 v = *(const float4*)(x + (long)c * PN + p0 + p4);
      xt[(p4 + 0) * 264 + cl] = f2bf(v.x);
      xt[(p4 + 1) * 264 + cl] = f2bf(v.y);
      xt[(p4 + 2) * 264 + cl] = f2bf(v.z);
      xt[(p4 + 3) * 264 + cl] = f2bf(v.w);
      ss0 += v.x * v.x; ss1 += v.y * v.y; ss2 += v.z * v.z; ss3 += v.w * v.w;
    }
    __syncthreads();
    // writeout: 64 rows x 256 el = 2048 16B-chunks, 8 per thread, coalesced
#pragma unroll
    for (int i = 0; i < 8; ++i) {
      int chunk = tid + i * 256;
      int r = chunk >> 5;                // 32 chunks per row
      int c8 = (chunk & 31) * 8;
      uint4 v = *(const uint4*)(&xt[r * 264 + c8]);
      *(uint4*)(xT + (p0 + r) * DIMC + half * 256 + c8) = v;
    }
  }
  red[cg * 64 + p4 + 0] = ss0;
  red[cg * 64 + p4 + 1] = ss1;
  red[cg * 64 + p4 + 2] = ss2;
  red[cg * 64 + p4 + 3] = ss3;
  __syncthreads();
  if (tid < 64) {
    float t = 0.f;
#pragma unroll
    for (int g = 0; g < 16; ++g) t += red[g * 64 + tid];
    s[p0 + tid] = SQRTC / fmaxf(sqrtf(t), 1e-12f);
  }
}

// ---------------- fast MFMA GEMM (m97-style, B^T input, both k-contiguous, K=512):
//   D[m][n] = sum_k A[m][k] * BT[n][k]
// EPI 0: C[m*Nstr+n] = bf16(D * gamma[n])                      (weight fusion)
// EPI 1: C[m*Nstr+n] = f32(xid[m*Nstr+n] + fb[m] + s[n] * D)   (main)
template <int EPI>
__global__ __launch_bounds__(256) void k_gemm_f(
    const ushort_t* __restrict__ A,    // [M][512] bf16
    const ushort_t* __restrict__ BT,   // [N][512] bf16
    long Nstr,
    void* __restrict__ Cv,
    const float* __restrict__ gamma,
    const float* __restrict__ xid,
    const float* __restrict__ fb,
    const float* __restrict__ s) {
  __shared__ ushort_t As[128 * 64];    // [row][64k], 16B-chunk XOR swizzle
  __shared__ ushort_t Bs[128 * 64];
  int tid = threadIdx.x;
  int p0 = blockIdx.x * 128;
  int o0 = blockIdx.y * 128;
  int wave = tid >> 6, lane = tid & 63;
  int wo = (wave & 1) * 64, wp = (wave >> 1) * 64;
  int q = lane >> 4, ln = lane & 15;

  f32x4 zero = {0.f, 0.f, 0.f, 0.f};
  f32x4 acc[4][4];
#pragma unroll
  for (int i = 0; i < 4; ++i)
#pragma unroll
    for (int j = 0; j < 4; ++j) acc[i][j] = zero;

  int sr = tid >> 3;                   // staging row 0..31 per sweep
  int sc = tid & 7;                    // 16B chunk 0..7
  const ushort_t* Ag = A + (long)(o0 + sr) * DIMC + sc * 8;
  const ushort_t* Bg = BT + (long)(p0 + sr) * DIMC + sc * 8;

  for (int kc = 0; kc < DIMC; kc += 64) {
    __syncthreads();
#pragma unroll
    for (int it = 0; it < 4; ++it) {
      int r = sr + it * 32;
      uint4 va = *(const uint4*)(Ag + (long)it * 32 * DIMC + kc);
      uint4 vb = *(const uint4*)(Bg + (long)it * 32 * DIMC + kc);
      int sw = ((sc ^ (r & 7)) * 8);
      *(uint4*)(&As[r * 64 + sw]) = va;
      *(uint4*)(&Bs[r * 64 + sw]) = vb;
    }
    __syncthreads();
#pragma unroll
    for (int ks = 0; ks < 2; ++ks) {
      int cch = ks * 4 + q;            // 16B chunk index 0..7
      short8 af[4], bf[4];
#pragma unroll
      for (int mi = 0; mi < 4; ++mi) {
        int row = wo + mi * 16 + ln;
        af[mi] = *(const short8*)(&As[row * 64 + ((cch ^ (row & 7)) * 8)]);
      }
#pragma unroll
      for (int ni = 0; ni < 4; ++ni) {
        int row = wp + ni * 16 + ln;
        bf[ni] = *(const short8*)(&Bs[row * 64 + ((cch ^ (row & 7)) * 8)]);
      }
#pragma unroll
      for (int mi = 0; mi < 4; ++mi)
#pragma unroll
        for (int ni = 0; ni < 4; ++ni)
          acc[mi][ni] = __builtin_amdgcn_mfma_f32_16x16x32_bf16(af[mi], bf[ni], acc[mi][ni], 0, 0, 0);
    }
  }

#pragma unroll
  for (int mi = 0; mi < 4; ++mi) {
    int obase = o0 + wo + mi * 16 + q * 4;
#pragma unroll
    for (int ni = 0; ni < 4; ++ni) {
      int p = p0 + wp + ni * 16 + ln;
      if (EPI == 0) {
        ushort_t* C = (ushort_t*)Cv;
        float g = gamma[p];
#pragma unroll
        for (int r = 0; r < 4; ++r)
          C[(long)(obase + r) * Nstr + p] = f2bf(acc[mi][ni][r] * g);
      } else {
        float* C = (float*)Cv;
        float sv = s[p];
#pragma unroll
        for (int r = 0; r < 4; ++r) {
          int o = obase + r;
          C[(long)o * Nstr + p] = xid[(long)o * Nstr + p] + fb[o] + sv * acc[mi][ni][r];
        }
      }
    }
  }
}

extern "C" void kernel_launch(void* const* d_in, const int* in_sizes, int n_in,
                              void* d_out, int out_size, void* d_ws, size_t ws_size,
                              hipStream_t stream) {
  const float* x     = (const float*)d_in[0];
  const float* gamma = (const float*)d_in[1];
  const float* wqkv  = (const float*)d_in[2];
  const float* bqkv  = (const float*)d_in[3];
  const float* wproj = (const float*)d_in[4];
  const float* bproj = (const float*)d_in[5];

  char* ws = (char*)d_ws;
  ushort_t* Mp  = (ushort_t*)(ws);             // 512*512 bf16  (524288 B)
  ushort_t* wpb = (ushort_t*)(ws + 524288);    // 512*512 bf16
  ushort_t* WvT = (ushort_t*)(ws + 1048576);   // 512*512 bf16
  float*    fb  = (float*)(ws + 1572864);      // 512 f32
  float*    s   = (float*)(ws + 1576960);      // 32768 f32
  ushort_t* xT  = (ushort_t*)(ws + 2097152);   // 32768*512 bf16 (32 MB)

  k_cast<<<dim3(256), dim3(256), 0, stream>>>(wproj, wpb);
  k_wvt<<<dim3(512), dim3(64), 0, stream>>>(wqkv, WvT);
  k_fb<<<dim3(128), dim3(256), 0, stream>>>(wproj, bqkv, bproj, fb);
  k_prep_x<<<dim3(512), dim3(256), 0, stream>>>(x, xT, s);
  // Mp[o][c] = (sum_k wpb[o,k] * WvT[c,k]) * gamma[c]
  k_gemm_f<0><<<dim3(4, 4), dim3(256), 0, stream>>>(
      wpb, WvT, 512, Mp, gamma, nullptr, nullptr, nullptr);
  // out[o][p] = x[o][p] + fb[o] + s[p] * sum_c Mp[o,c]*xT[p,c]
  k_gemm_f<1><<<dim3(256, 4), dim3(256), 0, stream>>>(
      Mp, xT, PN, d_out, nullptr, x, fb, s);
}